// Round 7
// baseline (1176.181 us; speedup 1.0000x reference)
//
#include <hip/hip_runtime.h>
#include <hip/hip_bf16.h>
#include <cstdint>
#include <cstddef>

#define B_ROWS 16384
#define WIDTH  1024
#define HID    2048
#define NBLK   4
#define YDIM   16
#define OUTD   256
#define KIN    128          // input dim 81 padded to 128
#define MAXM_PER_CLASS 4096

typedef __attribute__((ext_vector_type(8))) short short8;
typedef __attribute__((ext_vector_type(4))) float f32x4;

#define FENCE() asm volatile("" ::: "memory")
#define BAR()   do { FENCE(); __builtin_amdgcn_s_barrier(); FENCE(); } while (0)
#define VM6()   asm volatile("s_waitcnt vmcnt(6)" ::: "memory")
#define VM0()   asm volatile("s_waitcnt vmcnt(0)" ::: "memory")

__device__ __forceinline__ unsigned short f2bf(float f) {
    union { float f; uint32_t u; } v; v.f = f;
    uint32_t u = v.u;
    uint32_t r = (u + 0x7FFFu + ((u >> 16) & 1u)) >> 16;
    return (unsigned short)r;
}

__device__ __forceinline__ void gload_lds16(const void* g, void* l) {
    __builtin_amdgcn_global_load_lds(
        (const __attribute__((address_space(1))) void*)g,
        (__attribute__((address_space(3))) void*)l, 16, 0, 0);
}

// ---------------------------------------------------------------------------
// x build only (no atomics): padded bf16 rows [B,128] = [theta|lambda|y_oh|0]
__global__ __launch_bounds__(256)
void prep_x_k(const float* __restrict__ theta, const float* __restrict__ lam,
              const float* __restrict__ yoh, unsigned short* __restrict__ xb)
{
    int tid = threadIdx.x;
    int row = blockIdx.x * 2 + (tid >> 7);
    int j = tid & 127;
    float v;
    if (j < 64)       v = theta[(size_t)row * 64 + j];
    else if (j == 64) v = lam[row];
    else if (j < 81)  v = yoh[(size_t)row * 16 + (j - 65)];
    else              v = 0.f;
    xb[(size_t)row * KIN + j] = f2bf(v);
}

// ---------------------------------------------------------------------------
// argmax-route rows into per-class buckets; LDS-aggregated histogram, one
// global atomic per (block, class) to cache-line-padded counters.
__global__ __launch_bounds__(256)
void bucket_k(const float* __restrict__ yoh, int* __restrict__ counts,
              int* __restrict__ bucket)
{
    __shared__ int cnt_lds[16];
    __shared__ int base_lds[16];
    int tid = threadIdx.x;
    if (tid < 16) cnt_lds[tid] = 0;
    __syncthreads();
    int row = blockIdx.x * 256 + tid;
    const float4* yr = (const float4*)(yoh + (size_t)row * 16);
    int best = 0; float bv = -3.0e38f;
    #pragma unroll
    for (int p = 0; p < 4; ++p) {
        float4 v = yr[p];
        if (v.x > bv) { bv = v.x; best = p * 4 + 0; }
        if (v.y > bv) { bv = v.y; best = p * 4 + 1; }
        if (v.z > bv) { bv = v.z; best = p * 4 + 2; }
        if (v.w > bv) { bv = v.w; best = p * 4 + 3; }
    }
    int mypos = atomicAdd(&cnt_lds[best], 1);
    __syncthreads();
    if (tid < 16) base_lds[tid] = atomicAdd(&counts[tid * 32], cnt_lds[tid]);
    __syncthreads();
    int pos = base_lds[best] + mypos;
    if (pos < MAXM_PER_CLASS) bucket[best * MAXM_PER_CLASS + pos] = row;
}

// ---------------------------------------------------------------------------
// batched transpose + fp32->bf16: src [R][C] -> dst [C][RP], zero-padding rows R..RP
__global__ __launch_bounds__(256)
void tcvt_k(const float* __restrict__ src, unsigned short* __restrict__ dst,
            int R, int C, int RP)
{
    int b = blockIdx.z;
    src += (size_t)b * R * C;
    dst += (size_t)b * C * RP;
    __shared__ float tile[32][33];
    int tx = threadIdx.x & 31, ty = threadIdx.x >> 5;   // 32 x 8
    int c0 = blockIdx.x * 32, r0 = blockIdx.y * 32;
    #pragma unroll
    for (int p = 0; p < 4; ++p) {
        int r = r0 + p * 8 + ty;
        float v = (r < R) ? src[(size_t)r * C + c0 + tx] : 0.f;
        tile[p * 8 + ty][tx] = v;
    }
    __syncthreads();
    #pragma unroll
    for (int p = 0; p < 4; ++p) {
        int c = c0 + p * 8 + ty;
        dst[(size_t)c * RP + r0 + tx] = f2bf(tile[tx][p * 8 + ty]);
    }
}

// ---------------------------------------------------------------------------
// LayerNorm: h fp32 [B,1024] -> z bf16 [B,1024]
__global__ __launch_bounds__(256)
void ln_k(const float* __restrict__ h, const float* __restrict__ g,
          const float* __restrict__ bb, unsigned short* __restrict__ z)
{
    int row = blockIdx.x;
    int t = threadIdx.x;
    const float4 v = ((const float4*)(h + (size_t)row * WIDTH))[t];
    float s  = v.x + v.y + v.z + v.w;
    float s2 = v.x * v.x + v.y * v.y + v.z * v.z + v.w * v.w;
    #pragma unroll
    for (int off = 32; off > 0; off >>= 1) {
        s  += __shfl_down(s, off);
        s2 += __shfl_down(s2, off);
    }
    __shared__ float red[8];
    int wv = t >> 6;
    if ((t & 63) == 0) { red[wv] = s; red[4 + wv] = s2; }
    __syncthreads();
    float st = 0.f, s2t = 0.f;
    #pragma unroll
    for (int i = 0; i < 4; ++i) { st += red[i]; s2t += red[4 + i]; }
    float mu  = st * (1.f / 1024.f);
    float var = s2t * (1.f / 1024.f) - mu * mu;
    float rs  = rsqrtf(var + 1e-5f);
    float4 gg  = ((const float4*)g)[t];
    float4 bbv = ((const float4*)bb)[t];
    ushort4 o;
    o.x = f2bf((v.x - mu) * rs * gg.x + bbv.x);
    o.y = f2bf((v.y - mu) * rs * gg.y + bbv.y);
    o.z = f2bf((v.z - mu) * rs * gg.z + bbv.z);
    o.w = f2bf((v.w - mu) * rs * gg.w + bbv.w);
    ((ushort4*)(z + (size_t)row * WIDTH))[t] = o;
}

// ---------------------------------------------------------------------------
// 128x256x(BK=64) bf16 MFMA GEMM, 512 threads (8 waves, 2M x 4N, 64x64/wave),
// TRIPLE-buffered LDS (144 KiB), depth-2 prefetch with truly-counted vmcnt:
// tile kt is staged 2 iterations before use, so the top-of-loop vmcnt(6)
// (= only tile kt+1's 6 loads may remain in flight) is a no-op in steady
// state. ONE barrier per K-tile; K-tile body is flat (C++ ds_reads + MFMA,
// compiler emits fine-grained lgkmcnt interleave). setprio around MFMA (T5).
// Hazards: WAR on buf[(kt+2)%3]==buf[(kt-1)%3] fenced by the barrier (all
// waves consumed their kt-1 reads before arriving); RAW on tile kt by
// vmcnt gate + barrier; tail iterations use vmcnt(0)/skip-stage.
// EPI: 1 = +bias, SiLU -> Cb (bf16)
//      2 = Cf += rscale*( . + bias); optional Cb = bf16(Cf)
template<int EPI>
__global__ __launch_bounds__(512, 2)
void gemm3_k(const short* __restrict__ A, const short* __restrict__ BT,
             const float* __restrict__ bias,
             float* __restrict__ Cf, unsigned short* __restrict__ Cb,
             const float* __restrict__ rs_ptr, int rs_idx, int writeHb,
             int N, int K, int ntN)
{
    __shared__ short lsA[3][128 * 64];
    __shared__ short lsB[3][256 * 64];

    int tid = threadIdx.x;
    int w = tid >> 6, lane = tid & 63;

    int nwg = gridDim.x;
    int wg  = blockIdx.x;
    int cpx = nwg >> 3;                          // grids are %8==0
    int swz = (wg & 7) * cpx + (wg >> 3);        // bijective XCD swizzle
    int bm = swz / ntN, bn = swz % ntN;

    const int wm = w >> 2, wn = w & 3;           // wave tile 64(M) x 64(N)
    const int sr = lane >> 3;                    // 0..7
    const int ss = lane & 7;                     // 0..7
    const int nkt = K >> 6;

    f32x4 acc[4][4];
    #pragma unroll
    for (int i = 0; i < 4; ++i)
        #pragma unroll
        for (int j = 0; j < 4; ++j) acc[i][j] = (f32x4)(0.f);

    // stage one K-tile: A 128x64 (2 gload_lds/thread) + B 256x64 (4/thread)
    // XOR-swizzled content via pre-swizzled per-lane global source; LDS dest
    // is wave-uniform base + lane*16 as gload_lds requires.
    auto STAGE = [&](int buf, int kt) {
        #pragma unroll
        for (int c = 0; c < 2; ++c) {
            int r  = c * 64 + w * 8 + sr;
            int sg = ss ^ (r & 7);
            const short* ga = A + (size_t)(bm * 128 + r) * K + (size_t)kt * 64 + sg * 8;
            gload_lds16(ga, &lsA[buf][(c * 64 + w * 8) * 64]);
        }
        #pragma unroll
        for (int c = 0; c < 4; ++c) {
            int r  = c * 64 + w * 8 + sr;
            int sg = ss ^ (r & 7);
            const short* gb = BT + (size_t)(bn * 256 + r) * K + (size_t)kt * 64 + sg * 8;
            gload_lds16(gb, &lsB[buf][(c * 64 + w * 8) * 64]);
        }
    };

    // prologue: tiles 0 and 1 in flight (12 loads/thread outstanding)
    STAGE(0, 0);
    STAGE(1, 1);

    int cur = 0;
    for (int kt = 0; kt < nkt; ++kt) {
        // gate: tile kt landed (tile kt+1's 6 loads may stay in flight)
        if (kt + 1 < nkt) { VM6(); } else { VM0(); }
        BAR();
        int nxt = cur + 2; if (nxt >= 3) nxt -= 3;
        if (kt + 2 < nkt) STAGE(nxt, kt + 2);

        #pragma unroll
        for (int ks = 0; ks < 2; ++ks) {
            short8 af[4], bf[4];
            #pragma unroll
            for (int m = 0; m < 4; ++m) {
                int r = wm * 64 + m * 16 + (lane & 15);
                int s = ks * 4 + (lane >> 4);
                af[m] = *(const short8*)&lsA[cur][r * 64 + (s ^ (r & 7)) * 8];
            }
            #pragma unroll
            for (int n = 0; n < 4; ++n) {
                int r = wn * 64 + n * 16 + (lane & 15);
                int s = ks * 4 + (lane >> 4);
                bf[n] = *(const short8*)&lsB[cur][r * 64 + (s ^ (r & 7)) * 8];
            }
            __builtin_amdgcn_s_setprio(1);
            #pragma unroll
            for (int m = 0; m < 4; ++m)
                #pragma unroll
                for (int n = 0; n < 4; ++n)
                    acc[m][n] = __builtin_amdgcn_mfma_f32_16x16x32_bf16(af[m], bf[n], acc[m][n], 0, 0, 0);
            __builtin_amdgcn_s_setprio(0);
        }

        cur = (cur == 2) ? 0 : cur + 1;
    }

    float rscale = (EPI == 2) ? rs_ptr[rs_idx] : 0.f;
    #pragma unroll
    for (int m = 0; m < 4; ++m) {
        #pragma unroll
        for (int reg = 0; reg < 4; ++reg) {
            int lr = wm * 64 + m * 16 + (lane >> 4) * 4 + reg;
            #pragma unroll
            for (int n = 0; n < 4; ++n) {
                int lc = wn * 64 + n * 16 + (lane & 15);
                float v = acc[m][n][reg];
                size_t idx = ((size_t)bm * 128 + lr) * (size_t)N + bn * 256 + lc;
                float x = v + bias[bn * 256 + lc];
                if (EPI == 1) {
                    Cb[idx] = f2bf(x / (1.f + __expf(-x)));
                } else {
                    float hv = Cf[idx] + rscale * x;
                    Cf[idx] = hv;
                    if (writeHb) Cb[idx] = f2bf(hv);
                }
            }
        }
    }
}

// ---------------------------------------------------------------------------
// 128x128x(BK=64) bf16 MFMA GEMM (small shapes), double-buffered, 2-phase.
// EPI: 0 = +bias, GELU -> Cf (fp32)
//      3 = bucketed head: gathered A rows, out = . + bias (fp32), masked
template<int EPI>
__global__ __launch_bounds__(256)
void gemm_k(const short* __restrict__ A, const short* __restrict__ BT,
            const float* __restrict__ bias,
            float* __restrict__ Cf,
            const int* __restrict__ counts, const int* __restrict__ bucket,
            float* __restrict__ outp,
            int N, int K, int ntN)
{
    __shared__ short lsA[2][128 * 64];
    __shared__ short lsB[2][128 * 64];
    __shared__ int rowsLds[128];

    int tid = threadIdx.x;
    int w = tid >> 6, lane = tid & 63;

    int bm = 0, bn = 0, m0 = 0, cnt = 0;
    if (EPI == 3) {
        int cls = blockIdx.z;
        cnt = counts[cls * 32];
        if (cnt > MAXM_PER_CLASS) cnt = MAXM_PER_CLASS;
        m0 = blockIdx.y * 128;
        if (m0 >= cnt) return;                       // uniform exit (before any barrier)
        bn = blockIdx.x;
        if (tid < 128) rowsLds[tid] = bucket[cls * MAXM_PER_CLASS + m0 + tid];
        __syncthreads();
        BT   += (size_t)cls * OUTD * WIDTH;
        bias += cls * OUTD;
    } else {
        int nwg = gridDim.x;
        int wg  = blockIdx.x;
        int cpx = nwg >> 3;
        int swz = (wg & 7) * cpx + (wg >> 3);
        bm = swz / ntN; bn = swz % ntN;
    }

    const int sr = lane >> 3;
    const int ss = lane & 7;
    const int wm = w >> 1, wn = w & 1;
    const int nkt = K >> 6;

    f32x4 acc[4][4];
    #pragma unroll
    for (int i = 0; i < 4; ++i)
        #pragma unroll
        for (int j = 0; j < 4; ++j) acc[i][j] = (f32x4)(0.f);

    auto STAGE = [&](int buf, int kt) {
        #pragma unroll
        for (int c = 0; c < 4; ++c) {
            int r  = w * 32 + c * 8 + sr;
            int sg = ss ^ (r & 7);
            long grow = (EPI == 3) ? (long)rowsLds[r] : ((long)bm * 128 + r);
            const short* ga = A + (size_t)grow * K + (size_t)kt * 64 + sg * 8;
            gload_lds16(ga, &lsA[buf][(w * 32 + c * 8) * 64]);
        }
        #pragma unroll
        for (int c = 0; c < 4; ++c) {
            int r  = w * 32 + c * 8 + sr;
            int sg = ss ^ (r & 7);
            const short* gb = BT + (size_t)(bn * 128 + r) * K + (size_t)kt * 64 + sg * 8;
            gload_lds16(gb, &lsB[buf][(w * 32 + c * 8) * 64]);
        }
    };

    STAGE(0, 0);
    VM0();
    __builtin_amdgcn_s_barrier();

    int cur = 0;
    for (int kt = 0; kt < nkt; ++kt) {
        if (kt + 1 < nkt) STAGE(cur ^ 1, kt + 1);

        #pragma unroll
        for (int ks = 0; ks < 2; ++ks) {
            short8 af[4], bf[4];
            #pragma unroll
            for (int m = 0; m < 4; ++m) {
                int r = wm * 64 + m * 16 + (lane & 15);
                int s = ks * 4 + (lane >> 4);
                af[m] = *(const short8*)&lsA[cur][r * 64 + (s ^ (r & 7)) * 8];
            }
            #pragma unroll
            for (int n = 0; n < 4; ++n) {
                int r = wn * 64 + n * 16 + (lane & 15);
                int s = ks * 4 + (lane >> 4);
                bf[n] = *(const short8*)&lsB[cur][r * 64 + (s ^ (r & 7)) * 8];
            }
            __builtin_amdgcn_s_setprio(1);
            #pragma unroll
            for (int m = 0; m < 4; ++m)
                #pragma unroll
                for (int n = 0; n < 4; ++n)
                    acc[m][n] = __builtin_amdgcn_mfma_f32_16x16x32_bf16(af[m], bf[n], acc[m][n], 0, 0, 0);
            __builtin_amdgcn_s_setprio(0);
        }

        VM0();
        __builtin_amdgcn_s_barrier();
        cur ^= 1;
    }

    #pragma unroll
    for (int m = 0; m < 4; ++m) {
        #pragma unroll
        for (int reg = 0; reg < 4; ++reg) {
            int lr = wm * 64 + m * 16 + (lane >> 4) * 4 + reg;
            #pragma unroll
            for (int n = 0; n < 4; ++n) {
                int lc = wn * 64 + n * 16 + (lane & 15);
                float v = acc[m][n][reg];
                if (EPI == 0) {
                    size_t idx = ((size_t)bm * 128 + lr) * (size_t)N + bn * 128 + lc;
                    float x = v + bias[bn * 128 + lc];
                    Cf[idx] = 0.5f * x * (1.f + erff(x * 0.70710678118f));
                } else {
                    if (m0 + lr < cnt) {
                        int orow = rowsLds[lr];
                        int oc = bn * 128 + lc;
                        outp[(size_t)orow * OUTD + oc] = v + bias[oc];
                    }
                }
            }
        }
    }
}

// ---------------------------------------------------------------------------
extern "C" void kernel_launch(void* const* d_in, const int* in_sizes, int n_in,
                              void* d_out, int out_size, void* d_ws, size_t ws_size,
                              hipStream_t stream)
{
    const float* theta = (const float*)d_in[0];
    const float* lam   = (const float*)d_in[1];
    const float* yoh   = (const float*)d_in[2];
    const float* W_in  = (const float*)d_in[3];
    const float* b_in  = (const float*)d_in[4];
    const float* ln_g  = (const float*)d_in[5];
    const float* ln_b  = (const float*)d_in[6];
    const float* w1    = (const float*)d_in[7];
    const float* b1    = (const float*)d_in[8];
    const float* w2    = (const float*)d_in[9];
    const float* b2    = (const float*)d_in[10];
    const float* rsc   = (const float*)d_in[11];
    const float* Wh    = (const float*)d_in[12];
    const float* bh    = (const float*)d_in[13];
    float* out = (float*)d_out;

    char* p = (char*)d_ws;
    auto alloc = [&](size_t bytes) -> char* {
        char* r = p; p += (bytes + 255) & ~(size_t)255; return r;
    };
    float*          h    = (float*)         alloc((size_t)B_ROWS * WIDTH * 4);
    unsigned short* hb   = (unsigned short*)alloc((size_t)B_ROWS * WIDTH * 2);
    unsigned short* z    = (unsigned short*)alloc((size_t)B_ROWS * WIDTH * 2);
    unsigned short* t    = (unsigned short*)alloc((size_t)B_ROWS * HID * 2);
    unsigned short* xb   = (unsigned short*)alloc((size_t)B_ROWS * KIN * 2);
    unsigned short* w1T  = (unsigned short*)alloc((size_t)NBLK * HID * WIDTH * 2);
    unsigned short* w2T  = (unsigned short*)alloc((size_t)NBLK * WIDTH * HID * 2);
    unsigned short* WhT  = (unsigned short*)alloc((size_t)YDIM * OUTD * WIDTH * 2);
    unsigned short* WiT  = (unsigned short*)alloc((size_t)WIDTH * KIN * 2);
    int*            bucket = (int*)alloc((size_t)YDIM * MAXM_PER_CLASS * 4);
    int*            counts = (int*)alloc(16 * 32 * 4);

    hipMemsetAsync(bucket, 0, (size_t)YDIM * MAXM_PER_CLASS * 4, stream);
    hipMemsetAsync(counts, 0, 16 * 32 * 4, stream);

    // prep inputs + buckets
    prep_x_k<<<B_ROWS / 2, 256, 0, stream>>>(theta, lam, yoh, xb);
    bucket_k<<<B_ROWS / 256, 256, 0, stream>>>(yoh, counts, bucket);

    // weight conversions (transpose to [N][K] bf16)
    tcvt_k<<<dim3(WIDTH / 32, KIN / 32, 1),    256, 0, stream>>>(W_in, WiT, 81,   WIDTH, KIN);
    tcvt_k<<<dim3(HID / 32,   WIDTH / 32, 4),  256, 0, stream>>>(w1,   w1T, WIDTH, HID,  WIDTH);
    tcvt_k<<<dim3(WIDTH / 32, HID / 32, 4),    256, 0, stream>>>(w2,   w2T, HID,  WIDTH, HID);
    tcvt_k<<<dim3(OUTD / 32,  WIDTH / 32, 16), 256, 0, stream>>>(Wh,   WhT, WIDTH, OUTD, WIDTH);

    // input GEMM + GELU -> h fp32 (128^2 kernel; K=128 too small for prefetch depth)
    gemm_k<0><<<(B_ROWS / 128) * (WIDTH / 128), 256, 0, stream>>>(
        (const short*)xb, (const short*)WiT, b_in, h,
        nullptr, nullptr, nullptr, WIDTH, KIN, WIDTH / 128);

    for (int i = 0; i < NBLK; ++i) {
        ln_k<<<B_ROWS, 256, 0, stream>>>(h, ln_g + i * WIDTH, ln_b + i * WIDTH, z);
        gemm3_k<1><<<(B_ROWS / 128) * (HID / 256), 512, 0, stream>>>(
            (const short*)z, (const short*)(w1T + (size_t)i * HID * WIDTH), b1 + i * HID,
            nullptr, t, nullptr, 0, 0, HID, WIDTH, HID / 256);
        gemm3_k<2><<<(B_ROWS / 128) * (WIDTH / 256), 512, 0, stream>>>(
            (const short*)t, (const short*)(w2T + (size_t)i * WIDTH * HID), b2 + i * WIDTH,
            h, hb, rsc, i, (i == NBLK - 1) ? 1 : 0, WIDTH, HID, WIDTH / 256);
    }

    // bucketed head GEMM
    gemm_k<3><<<dim3(OUTD / 128, MAXM_PER_CLASS / 128, YDIM), 256, 0, stream>>>(
        (const short*)hb, (const short*)WhT, bh, nullptr,
        counts, bucket, out, OUTD, WIDTH, OUTD / 128);

    (void)in_sizes; (void)n_in; (void)out_size; (void)ws_size; (void)rsc;
}